// Round 2
// 222.126 us; speedup vs baseline: 1.0690x; 1.0690x over previous
//
#include <hip/hip_runtime.h>
#include <math.h>

#define NBB 128
#define NAA 5
#define NCC 80
#define NHH 28
#define NWW 28
#define NTT 50
#define CH  85            // 5 + NC
#define HW  784           // NH*NW
#define CELLS 3920        // NA*NH*NW

__constant__ float c_AW[5] = {2.8f, 5.1f, 6.4f, 9.2f, 14.1f};
__constant__ float c_AH[5] = {4.8f, 10.2f, 16.3f, 19.8f, 23.7f};

__device__ __forceinline__ float sigmoidf_(float x) {
    return 1.0f / (1.0f + __expf(-x));
}

__device__ __forceinline__ float smooth_l1(float d) {
    float ad = fabsf(d);
    return (ad < 1.0f) ? 0.5f * d * d : ad - 0.5f;
}

// ---------------------------------------------------------------------------
// Fused kernel v2: grid (4, NB), block 1024 (16 waves) -> 512 blocks = 2/CU.
//
// Stage 1: threads 0..49 compute per-target records into LDS (4x redundant
//          across x-blocks, was 16x). Packed layouts:
//            boxS[j]  = float4(L,R,T,B)          -> one ds_read_b128/iter
//            s6[j]    = 0.375*area               -> sigil test is add+cmp
//            ctS[j]   = float2(cellbits, tconf)  -> one ds_read_b64/iter
// Stage 2: single fused 50-iter loop per cell: noobject sigil test
//          (inter > 0.375*(a1+a2)  <=>  iou > 0.6, division-free) and
//          assigned-cell scan (ascending j, last match wins) together.
//          Clamped product fmax(cw,0)*fmax(ch,0) replaces the cmp/and/select.
// Stage 3: wave w of x-block bx owns record j = bx*16+w (64 slots >= 50):
//          focal 80-class loss (lanes = classes) + smooth-L1 coord loss.
// Reduction: 64-lane shuffle reduce per wave, 16-slot LDS pass, one
//          atomicAdd per block (512 total, was 2048 same-address atomics).
// ---------------------------------------------------------------------------
__global__ __launch_bounds__(1024) void region_loss_fused(
    const float* __restrict__ out, const float* __restrict__ tgt,
    float* __restrict__ d_out)
{
    __shared__ float4 boxS[NTT];      // (L, R, T, B)
    __shared__ float  s6[NTT];        // 0.375 * gt area
    __shared__ float2 ctS[NTT];       // (cell as int bits, tconf)
    __shared__ int    rCell[NTT];
    __shared__ float  rTx[NTT], rTy[NTT], rTw[NTT], rTh[NTT];
    __shared__ int    rCls[NTT];
    __shared__ unsigned char rActive[NTT];
    __shared__ float  wred[16];

    const int b   = blockIdx.y;
    const int tid = threadIdx.x;

    // ---- Stage 1: per-target prep ----
    if (tid < NTT) {
        const float* tp = tgt + b * NTT * 5 + tid * 5;
        float cls = tp[0];
        float gx = tp[1] * NWW;
        float gy = tp[2] * NHH;
        float gw = tp[3] * NWW;
        float gh = tp[4] * NHH;
        float ga = gw * gh;

        boxS[tid] = make_float4(gx - gw * 0.5f, gx + gw * 0.5f,
                                gy - gh * 0.5f, gy + gh * 0.5f);
        s6[tid] = 0.375f * ga;        // 0.6/1.6 = 0.375 exactly

        // best anchor: IoU of (0,0,gw,gh) vs (0,0,aw,ah); first max wins
        int best = 0; float bestI = -1.0f;
        #pragma unroll
        for (int a = 0; a < 5; ++a) {
            float inter = fminf(gw, c_AW[a]) * fminf(gh, c_AH[a]);
            float uni   = ga + c_AW[a] * c_AH[a] - inter;
            float iou   = inter / uni;
            if (iou > bestI) { bestI = iou; best = a; }
        }
        int gi = (int)floorf(gx);
        int gj = (int)floorf(gy);
        int cell = (best * NHH + gj) * NWW + gi;

        // assigned predicted box (4 gathered loads)
        const float* op = out + ((size_t)(b * NAA + best) * CH) * HW + gj * NWW + gi;
        float px = sigmoidf_(op[0])      + (float)gi;
        float py = sigmoidf_(op[HW])     + (float)gj;
        float pw = __expf(op[2 * HW]) * c_AW[best];
        float ph = __expf(op[3 * HW]) * c_AH[best];

        float mx = fminf(px - pw * 0.5f, gx - gw * 0.5f);
        float Mx = fmaxf(px + pw * 0.5f, gx + gw * 0.5f);
        float my = fminf(py - ph * 0.5f, gy - gh * 0.5f);
        float My = fmaxf(py + ph * 0.5f, gy + gh * 0.5f);
        float cw  = pw + gw - (Mx - mx);
        float chh = ph + gh - (My - my);
        float inter = (cw > 0.f && chh > 0.f) ? cw * chh : 0.f;
        float uni   = pw * ph + ga - inter;

        rCell[tid] = cell;
        ctS[tid]   = make_float2(__int_as_float(cell), inter / uni);
        rTx[tid]   = gx - (float)gi;
        rTy[tid]   = gy - (float)gj;
        rTw[tid]   = __logf(gw / c_AW[best]);
        rTh[tid]   = __logf(gh / c_AH[best]);
        rCls[tid]  = (int)cls;
    }
    __syncthreads();

    if (tid < NTT) {
        int cell = rCell[tid];
        unsigned char active = 1;
        for (int t2 = tid + 1; t2 < NTT; ++t2)
            if (rCell[t2] == cell) active = 0;   // later record wins
        rActive[tid] = active;
    }

    // ---- Stage 2: conf loss over cells (fused sigil + assigned scan) ----
    const int cell = blockIdx.x * 1024 + tid;
    float term = 0.0f;

    if (cell < CELLS) {
        int a  = cell / HW;
        int hw = cell - a * HW;
        int wi = hw % NWW;
        int hj = hw / NWW;
        const float* op = out + ((size_t)(b * NAA + a) * CH) * HW + hw;

        float px   = sigmoidf_(op[0])  + (float)wi;
        float py   = sigmoidf_(op[HW]) + (float)hj;
        float pw   = __expf(op[2 * HW]) * c_AW[a];
        float ph   = __expf(op[3 * HW]) * c_AH[a];
        float conf = sigmoidf_(op[4 * HW]);

        float l1 = px - pw * 0.5f, r1 = px + pw * 0.5f;
        float t1 = py - ph * 0.5f, b1 = py + ph * 0.5f;
        float c1 = 0.375f * (pw * ph);

        bool flag = false, assigned = false;
        float tc = 0.f;
        #pragma unroll 5
        for (int j = 0; j < NTT; ++j) {
            float4 bx = boxS[j];                              // ds_read_b128
            float cw  = fminf(r1, bx.y) - fmaxf(l1, bx.x);
            float ch2 = fminf(b1, bx.w) - fmaxf(t1, bx.z);
            float inter = fmaxf(cw, 0.f) * fmaxf(ch2, 0.f);
            flag = flag || (inter > c1 + s6[j]);              // iou > 0.6
            float2 c2 = ctS[j];                               // ds_read_b64
            bool hit = (__float_as_int(c2.x) == cell);
            assigned = assigned || hit;
            tc = hit ? c2.y : tc;                             // last wins
        }

        if (assigned) { float d = conf - tc; term = 2.5f * d * d; }
        else if (!flag) { term = 0.5f * conf * conf; }
    }

    // ---- Stage 3: assigned-cell loss, one record per wave ----
    const int wave = tid >> 6;
    const int lane = tid & 63;
    const int j    = blockIdx.x * 16 + wave;   // 4*16 = 64 slots >= NTT
    float contrib = 0.0f;

    __syncthreads();   // rActive ready

    if (j < NTT && rActive[j]) {
        int rc = rCell[j];
        int a  = rc / HW;
        int hw = rc - a * HW;
        const float* op = out + ((size_t)(b * NAA + a) * CH) * HW + hw;

        // class logits: lane -> c=lane, plus c=64+lane for lane<16
        float l0  = op[(5 + lane) * HW];
        float l1c = (lane < 16) ? op[(5 + 64 + lane) * HW] : -INFINITY;

        float m = fmaxf(l0, l1c);
        for (int o = 32; o >= 1; o >>= 1) m = fmaxf(m, __shfl_xor(m, o));
        float s = __expf(l0 - m) + ((lane < 16) ? __expf(l1c - m) : 0.0f);
        for (int o = 32; o >= 1; o >>= 1) s += __shfl_xor(s, o);

        int t = rCls[j];                              // wave-uniform
        float lt = (t < 64) ? __shfl(l0, t) : __shfl(l1c, t - 64);
        float logpt = lt - m - __logf(s);
        float pt = __expf(logpt);
        float focal = -(1.0f - pt) * (1.0f - pt) * logpt;

        if (lane == 0) {
            float x = sigmoidf_(op[0]);
            float y = sigmoidf_(op[HW]);
            float w = op[2 * HW];
            float h = op[3 * HW];
            contrib = focal +
                      0.5f * (smooth_l1(x - rTx[j]) + smooth_l1(y - rTy[j]) +
                              smooth_l1(w - rTw[j]) + smooth_l1(h - rTh[j]));
        }
    }

    // ---- reduction: wave shuffle + 16-slot LDS + single atomic ----
    float v = term + ((lane == 0) ? contrib : 0.0f);
    #pragma unroll
    for (int o = 32; o >= 1; o >>= 1) v += __shfl_xor(v, o);
    if (lane == 0) wred[wave] = v;
    __syncthreads();
    if (tid == 0) {
        float s = 0.0f;
        #pragma unroll
        for (int w2 = 0; w2 < 16; ++w2) s += wred[w2];
        atomicAdd(d_out, s);
    }
}

extern "C" void kernel_launch(void* const* d_in, const int* in_sizes, int n_in,
                              void* d_out, int out_size, void* d_ws, size_t ws_size,
                              hipStream_t stream) {
    const float* out_p = (const float*)d_in[0];   // (128, 425, 28, 28)
    const float* tgt_p = (const float*)d_in[1];   // (128, 250)
    float* loss = (float*)d_out;

    hipMemsetAsync(loss, 0, (size_t)out_size * sizeof(float), stream);

    region_loss_fused<<<dim3(4, NBB), dim3(1024), 0, stream>>>(
        out_p, tgt_p, loss);
}